// Round 5
// baseline (122.294 us; speedup 1.0000x reference)
//
#include <hip/hip_runtime.h>
#include <stdint.h>

// Problem constants (from the reference)
constexpr int Tdim = 4096;   // time / input width
constexpr int Ndim = 4096;   // neurons
constexpr int Bdim = 1024;   // batch
constexpr int NB   = 16;     // address bits
constexpr int WPN  = 2115;   // words per neuron = ceil(65536 / 31)

// ---------------------------------------------------------------------------
// Per-wave layout probe: int64-on-device arrays (values < 2^31) have zero
// high halves at every odd int32 slot. 64 probes via ballot; false positive
// <= 2^-64. Returns the int32-index multiplier (2 = int64, 1 = int32).
// ---------------------------------------------------------------------------
__device__ __forceinline__ int probe_stride(const int* __restrict__ p) {
    const int l = threadIdx.x & 63;
    return (__ballot(p[2 * l + 1] == 0) == ~0ull) ? 2 : 1;
}

// ---------------------------------------------------------------------------
// Kernel 1: pack x (B x T of 0/1) into bit-planes:
//   xT[bg * T + t] = uint32 whose bit bl = x[(bg*32 + bl) * T + t]
// Coalesced reads (lane = t), 32 strided rows per thread.
// ---------------------------------------------------------------------------
__global__ __launch_bounds__(256) void pack_kernel(const int* __restrict__ x,
                                                   uint32_t* __restrict__ xT) {
    const int sx = probe_stride(x);
    const int t  = blockIdx.x * 256 + threadIdx.x;
    const int bg = blockIdx.y;
    uint32_t w = 0;
#pragma unroll
    for (int bl = 0; bl < 32; ++bl) {
        const size_t idx = ((size_t)(bg * 32 + bl) * Tdim + t) * sx;
        w |= (uint32_t)(x[idx] & 1) << bl;
    }
    xT[(size_t)bg * Tdim + t] = w;
}

// ---------------------------------------------------------------------------
// Kernel 2 (row-local): wave = one neuron, lane = batch-within-64-group.
//  - 16 conn indices loaded once per wave (wave-uniform, L1-broadcast)
//  - per 64-batch group: 16 broadcast xT reads -> per-lane 16-bit address
//    (addr = conn[0]..conn[15] MSB->LSB, matching the reference weights)
//  - one gather per lane into THIS wave's 16.9 KB memory row (L1/L2-hot:
//    all 1024 gathers of the wave hit the same row -> ~2.7x less line traffic
//    and per-CU working set 270 KB instead of 34 MB)
//  - LDS-staged coalesced int32 stores (harness reads d_out as np.int32)
// 16 waves/CU (2 blocks x 8 waves) for latency hiding.
// ---------------------------------------------------------------------------
__global__ __launch_bounds__(512) void row_kernel(const uint32_t* __restrict__ xT,
                                                  const int* __restrict__ conn,
                                                  const int* __restrict__ mem,
                                                  int* __restrict__ out) {
    const int sc = probe_stride(conn);
    const int sm = probe_stride(mem);

    const int l = threadIdx.x & 63;            // lane = batch within group
    const int w = threadIdx.x >> 6;            // wave 0..7
    const int n = blockIdx.x * 8 + w;          // neuron owned by this wave

    __shared__ int tile[64 * 9];               // [batch][neuron], pad 8->9

    // 16 connection indices, wave-uniform (cache-broadcast loads)
    int c[16];
    const int* cp = conn + (size_t)n * NB * sc;
#pragma unroll
    for (int j = 0; j < 16; ++j) c[j] = cp[j * sc];

    const int* mrow = mem + (size_t)n * WPN * sm;
    const int bit = l & 31;

    for (int g = 0; g < 16; ++g) {             // 64-batch groups
        // bit-plane slice for this half-wave (batches g*64+l)
        const uint32_t* xs = xT + (size_t)(g * 2 + (l >> 5)) * Tdim;
        uint32_t addr = 0;
#pragma unroll
        for (int j = 0; j < 16; ++j)
            addr = (addr << 1) | ((xs[c[j]] >> bit) & 1u);

        const uint32_t wi = addr / 31u;               // magic-mul
        const uint32_t sh = (addr - wi * 31u) * 2u;   // 0..60
        // int64 layout: low half at int32 index 2*wi (high half zero, matching
        // the reference's zero bits 31..62). Zero-extend so sh>=32 yields 0.
        const uint64_t wd = (uint32_t)mrow[(size_t)wi * sm];
        tile[l * 9 + w] = (int)((wd >> sh) & 3u);
        __syncthreads();
        // cooperative coalesced store: thread t -> row r=t/8, col c2=t%8
        const int r  = threadIdx.x >> 3;
        const int c2 = threadIdx.x & 7;
        out[(size_t)(g * 64 + r) * Ndim + blockIdx.x * 8 + c2] = tile[r * 9 + c2];
        __syncthreads();
    }
}

// ---------------------------------------------------------------------------
// Fallback (only if ws_size < 512 KB): direct per-(b,n) gather. Correct, slower.
// ---------------------------------------------------------------------------
__global__ __launch_bounds__(256) void direct_kernel(const int* __restrict__ x,
                                                     const int* __restrict__ conn,
                                                     const int* __restrict__ mem,
                                                     int* __restrict__ out) {
    const int sx = probe_stride(x);
    const int sc = probe_stride(conn);
    const int sm = probe_stride(mem);
    const int n  = blockIdx.x * 256 + threadIdx.x;   // lane = n -> coalesced store
    const int b  = blockIdx.y;
    const int* cp = conn + (size_t)n * NB * sc;
    const int* xr = x + (size_t)b * Tdim * sx;
    uint32_t addr = 0;
#pragma unroll
    for (int j = 0; j < 16; ++j)
        addr = (addr << 1) | (uint32_t)(xr[(size_t)cp[j * sc] * sx] & 1);
    const uint32_t wi = addr / 31u;
    const uint32_t sh = (addr - wi * 31u) * 2u;
    const uint64_t wd = (uint32_t)mem[((size_t)n * WPN + wi) * sm];
    out[(size_t)b * Ndim + n] = (int)((wd >> sh) & 3u);
}

// ---------------------------------------------------------------------------
extern "C" void kernel_launch(void* const* d_in, const int* in_sizes, int n_in,
                              void* d_out, int out_size, void* d_ws, size_t ws_size,
                              hipStream_t stream) {
    const int* x    = (const int*)d_in[0];       // (B, T) 0/1
    const int* conn = (const int*)d_in[1];       // (N, 16) indices < T
    const int* mem  = (const int*)d_in[2];       // (N, WPN), values < 2^31
    int*       out  = (int*)d_out;               // (B, N), read back as np.int32
    uint32_t*  xT   = (uint32_t*)d_ws;           // (B/32, T) bit-planes, 512 KB

    const size_t need = (size_t)(Bdim / 32) * Tdim * sizeof(uint32_t);
    if (ws_size >= need) {
        dim3 g1(Tdim / 256, Bdim / 32);          // 16 x 32 = 512 blocks
        pack_kernel<<<g1, 256, 0, stream>>>(x, xT);
        row_kernel<<<Ndim / 8, 512, 0, stream>>>(xT, conn, mem, out);
    } else {
        dim3 g3(Ndim / 256, Bdim);               // 16 x 1024 blocks
        direct_kernel<<<g3, 256, 0, stream>>>(x, conn, mem, out);
    }
}

// Round 7
// 115.929 us; speedup vs baseline: 1.0549x; 1.0549x over previous
//
#include <hip/hip_runtime.h>
#include <stdint.h>

// Problem constants (from the reference)
constexpr int Tdim = 4096;   // time / input width
constexpr int Ndim = 4096;   // neurons
constexpr int Bdim = 1024;   // batch
constexpr int NB   = 16;     // address bits
constexpr int WPN  = 2115;   // words per neuron = ceil(65536 / 31)

// ---------------------------------------------------------------------------
// Per-wave layout probe: int64-on-device arrays (values < 2^31) have zero
// high halves at every odd int32 slot. 64 probes via ballot; false positive
// <= 2^-64. Returns the int32-index multiplier (2 = int64, 1 = int32).
// ---------------------------------------------------------------------------
__device__ __forceinline__ int probe_stride(const int* __restrict__ p) {
    const int l = threadIdx.x & 63;
    return (__ballot(p[2 * l + 1] == 0) == ~0ull) ? 2 : 1;
}

// ---------------------------------------------------------------------------
// Kernel 1: pack x (B x T of 0/1) into bit-planes:
//   xT[bg * T + t] = uint32 whose bit bl = x[(bg*32 + bl) * T + t]
// ---------------------------------------------------------------------------
__global__ __launch_bounds__(256) void pack_kernel(const int* __restrict__ x,
                                                   uint32_t* __restrict__ xT) {
    const int sx = probe_stride(x);
    const int t  = blockIdx.x * 256 + threadIdx.x;
    const int bg = blockIdx.y;
    uint32_t w = 0;
#pragma unroll
    for (int bl = 0; bl < 32; ++bl) {
        const size_t idx = ((size_t)(bg * 32 + bl) * Tdim + t) * sx;
        w |= (uint32_t)(x[idx] & 1) << bl;
    }
    xT[(size_t)bg * Tdim + t] = w;
}

// ---------------------------------------------------------------------------
// Kernel 2 (row-local, deep-MLP): wave = one neuron x one batch-quarter.
// grid = (N/8) x 4;  block = 8 waves; 2048 blocks = 64 waves/CU nominal.
//  - 16 conn indices per wave (wave-uniform, L1-broadcast)
//  - 4 x 64-batch groups fully unrolled, NO barrier between them:
//    64 independent xT loads + 4 independent row-gathers in flight
//  - wave's 4 groups hit one 16.9 KB memory row (L1-resident after first);
//    cross-quarter re-reads hit L3 (69 MB table < 256 MB) -> HBM ~compulsory
//  - ONE __syncthreads, then cooperative coalesced store of the 256x8 tile
// ---------------------------------------------------------------------------
__global__ __launch_bounds__(512) void row_kernel(const uint32_t* __restrict__ xT,
                                                  const int* __restrict__ conn,
                                                  const int* __restrict__ mem,
                                                  int* __restrict__ out) {
    const int sc = probe_stride(conn);
    const int sm = probe_stride(mem);

    const int l = threadIdx.x & 63;            // lane = batch within group
    const int w = threadIdx.x >> 6;            // wave 0..7
    const int n = blockIdx.x * 8 + w;          // neuron owned by this wave

    __shared__ int tile[256 * 9];              // [local batch][neuron], pad 8->9

    // 16 connection indices, wave-uniform (cache-broadcast loads)
    int c[16];
    const int* cp = conn + (size_t)n * NB * sc;
#pragma unroll
    for (int j = 0; j < 16; ++j) c[j] = cp[j * sc];

    const int* mrow = mem + (size_t)n * WPN * sm;
    const int bit = l & 31;
    const int hi  = l >> 5;

#pragma unroll
    for (int gl = 0; gl < 4; ++gl) {           // 4 groups, no barriers inside
        const int g = blockIdx.y * 4 + gl;     // global 64-batch group
        const uint32_t* xs = xT + (size_t)(g * 2 + hi) * Tdim;
        uint32_t addr = 0;
#pragma unroll
        for (int j = 0; j < 16; ++j)
            addr = (addr << 1) | ((xs[c[j]] >> bit) & 1u);

        const uint32_t wi = addr / 31u;               // magic-mul
        const uint32_t sh = (addr - wi * 31u) * 2u;   // 0..60
        // int64 layout: low half at int32 index 2*wi (high half zero, matching
        // the reference's zero bits 31..62). Zero-extend so sh>=32 yields 0.
        const uint64_t wd = (uint32_t)mrow[(size_t)wi * sm];
        tile[(gl * 64 + l) * 9 + w] = (int)((wd >> sh) & 3u);
    }
    __syncthreads();

    // cooperative store: 256 rows x 8 cols; 8 lanes cover one 32 B row-segment
    const int col = threadIdx.x & 7;
    const int rr  = threadIdx.x >> 3;          // 0..63
#pragma unroll
    for (int r0 = 0; r0 < 256; r0 += 64) {
        const int lb = r0 + rr;                // local batch row
        out[(size_t)(blockIdx.y * 256 + lb) * Ndim + blockIdx.x * 8 + col] =
            tile[lb * 9 + col];
    }
}

// ---------------------------------------------------------------------------
// Fallback (only if ws_size < 512 KB): direct per-(b,n) gather. Correct, slower.
// ---------------------------------------------------------------------------
__global__ __launch_bounds__(256) void direct_kernel(const int* __restrict__ x,
                                                     const int* __restrict__ conn,
                                                     const int* __restrict__ mem,
                                                     int* __restrict__ out) {
    const int sx = probe_stride(x);
    const int sc = probe_stride(conn);
    const int sm = probe_stride(mem);
    const int n  = blockIdx.x * 256 + threadIdx.x;   // lane = n -> coalesced store
    const int b  = blockIdx.y;
    const int* cp = conn + (size_t)n * NB * sc;
    const int* xr = x + (size_t)b * Tdim * sx;
    uint32_t addr = 0;
#pragma unroll
    for (int j = 0; j < 16; ++j)
        addr = (addr << 1) | (uint32_t)(xr[(size_t)cp[j * sc] * sx] & 1);
    const uint32_t wi = addr / 31u;
    const uint32_t sh = (addr - wi * 31u) * 2u;
    const uint64_t wd = (uint32_t)mem[((size_t)n * WPN + wi) * sm];
    out[(size_t)b * Ndim + n] = (int)((wd >> sh) & 3u);
}

// ---------------------------------------------------------------------------
extern "C" void kernel_launch(void* const* d_in, const int* in_sizes, int n_in,
                              void* d_out, int out_size, void* d_ws, size_t ws_size,
                              hipStream_t stream) {
    const int* x    = (const int*)d_in[0];       // (B, T) 0/1
    const int* conn = (const int*)d_in[1];       // (N, 16) indices < T
    const int* mem  = (const int*)d_in[2];       // (N, WPN), values < 2^31
    int*       out  = (int*)d_out;               // (B, N), read back as np.int32
    uint32_t*  xT   = (uint32_t*)d_ws;           // (B/32, T) bit-planes, 512 KB

    const size_t need = (size_t)(Bdim / 32) * Tdim * sizeof(uint32_t);
    if (ws_size >= need) {
        dim3 g1(Tdim / 256, Bdim / 32);          // 16 x 32 = 512 blocks
        pack_kernel<<<g1, 256, 0, stream>>>(x, xT);
        dim3 g2(Ndim / 8, 4);                    // 512 x 4 = 2048 blocks
        row_kernel<<<g2, 512, 0, stream>>>(xT, conn, mem, out);
    } else {
        dim3 g3(Ndim / 256, Bdim);               // 16 x 1024 blocks
        direct_kernel<<<g3, 256, 0, stream>>>(x, conn, mem, out);
    }
}

// Round 8
// 115.917 us; speedup vs baseline: 1.0550x; 1.0001x over previous
//
#include <hip/hip_runtime.h>
#include <stdint.h>

// Problem constants (from the reference)
constexpr int Tdim = 4096;   // time / input width
constexpr int Ndim = 4096;   // neurons
constexpr int Bdim = 1024;   // batch
constexpr int NB   = 16;     // address bits
constexpr int WPN  = 2115;   // words per neuron = ceil(65536 / 31)

// ---------------------------------------------------------------------------
// Per-wave layout probe: int64-on-device arrays (values < 2^31) have zero
// high halves at every odd int32 slot. 64 probes via ballot; false positive
// <= 2^-64. Returns the int32-index multiplier (2 = int64, 1 = int32).
// ---------------------------------------------------------------------------
__device__ __forceinline__ int probe_stride(const int* __restrict__ p) {
    const int l = threadIdx.x & 63;
    return (__ballot(p[2 * l + 1] == 0) == ~0ull) ? 2 : 1;
}

// ---------------------------------------------------------------------------
// Kernel 1: pack x (B x T of 0/1) into bit-planes:
//   xT[bg * T + t] = uint32 whose bit bl = x[(bg*32 + bl) * T + t]
// ---------------------------------------------------------------------------
__global__ __launch_bounds__(256) void pack_kernel(const int* __restrict__ x,
                                                   uint32_t* __restrict__ xT) {
    const int sx = probe_stride(x);
    const int t  = blockIdx.x * 256 + threadIdx.x;
    const int bg = blockIdx.y;
    uint32_t w = 0;
#pragma unroll
    for (int bl = 0; bl < 32; ++bl) {
        const size_t idx = ((size_t)(bg * 32 + bl) * Tdim + t) * sx;
        w |= (uint32_t)(x[idx] & 1) << bl;
    }
    xT[(size_t)bg * Tdim + t] = w;
}

// ---------------------------------------------------------------------------
// Kernel 2 v3 (LDS-staged addresses): block = 16 waves = 16 neurons,
// 512 batches per block; grid = (N/16, B/512) = (256, 2) = 2 blocks/CU.
//
// Phase A (per wave, no barrier): 4 divergent-gather instructions fetch the
//   neuron's full 16-conn x 16-bg bit-matrix (256 words) -> LDS. ONE latency
//   exposure instead of r7's 16-deep serial chain of broadcast loads.
// Phase B (per wave): 8 passes x {16 LDS reads (~6cy) -> 16-bit addr ->
//   independent gather into the neuron's 16.9 KB memory row}. 8 gathers in
//   flight; results packed with two 64-bit ballots into LDS masks.
// Phase C (after one barrier): cooperative store phase writes 512x16 int32
//   as full 64-B lines (16 neurons/block = one line per batch row).
// ---------------------------------------------------------------------------
__global__ __launch_bounds__(1024) void row_kernel(const uint32_t* __restrict__ xT,
                                                   const int* __restrict__ conn,
                                                   const int* __restrict__ mem,
                                                   int* __restrict__ out) {
    const int sc = probe_stride(conn);
    const int sm = probe_stride(mem);

    const int tid = threadIdx.x;
    const int l   = tid & 63;              // lane
    const int w   = tid >> 6;              // wave 0..15 = local neuron
    const int n   = blockIdx.x * 16 + w;   // neuron owned by this wave
    const int by  = blockIdx.y;            // batch half (512 each)

    __shared__ uint32_t bits[16 * 256];    // [wave][j*16 + bgl]
    __shared__ uint64_t msk[2][16][9];     // [bitplane][wave][pass], pad 8->9

    // Phase A: lane l -> (j = k*4 + l/16, bgl = l%16); 4 gathers cover j=0..15
    const int jhi  = l >> 4;               // 0..3
    const int bgl  = l & 15;               // local 32-batch group
    const int cbase = n * NB * sc;
#pragma unroll
    for (int k = 0; k < 4; ++k) {
        const int j = k * 4 + jhi;
        const int c = conn[cbase + j * sc];            // 16-lane broadcast, L1-hot
        bits[w * 256 + j * 16 + bgl] =
            xT[(size_t)(by * 16 + bgl) * Tdim + c];    // divergent gather, L2/L3
    }
    // same-wave DS producer->consumer: in-order DS + compiler waitcnt, no barrier

    const int* mrow = mem + (size_t)n * WPN * sm;
    const uint32_t* myb = &bits[w * 256];
    const int hib = l >> 5;                // 0/1: which bg of the pass
    const int bit = l & 31;

#pragma unroll
    for (int p = 0; p < 8; ++p) {          // 8 x 64-batch passes, independent
        const int bg = p * 2 + hib;
        uint32_t addr = 0;
#pragma unroll
        for (int j = 0; j < 16; ++j)       // conn[0] = MSB (reference weights)
            addr = (addr << 1) | ((myb[j * 16 + bg] >> bit) & 1u);

        const uint32_t wi = addr / 31u;               // magic-mul
        const uint32_t sh = (addr - wi * 31u) * 2u;   // 0..60
        // int64 table: low half at int32 index 2*wi (high half zero, matching
        // the reference's zero bits 31..62). Zero-extend so sh>=32 yields 0.
        const uint64_t wd = (uint32_t)mrow[(size_t)wi * sm];
        const uint32_t v  = (uint32_t)((wd >> sh) & 3u);
        const uint64_t b0 = __ballot((v & 1u) != 0u);
        const uint64_t b1 = __ballot((v & 2u) != 0u);
        if (l == 0) { msk[0][w][p] = b0; msk[1][w][p] = b1; }
    }
    __syncthreads();

    // Phase C: 8192 outputs by 1024 threads x 8; consecutive tid -> consecutive
    // addresses (16 neurons fill one 64-B line per batch row).
    const int nl = tid & 15;               // local neuron column
    const int s  = tid >> 4;               // 0..63: batch within pass
#pragma unroll
    for (int q = 0; q < 8; ++q) {
        const uint64_t m0 = msk[0][nl][q];
        const uint64_t m1 = msk[1][nl][q];
        const int v = (int)((m0 >> s) & 1ull) | ((int)((m1 >> s) & 1ull) << 1);
        const int b = by * 512 + q * 64 + s;
        out[(size_t)b * Ndim + blockIdx.x * 16 + nl] = v;
    }
}

// ---------------------------------------------------------------------------
// Fallback (only if ws_size < 512 KB): direct per-(b,n) gather. Correct, slower.
// ---------------------------------------------------------------------------
__global__ __launch_bounds__(256) void direct_kernel(const int* __restrict__ x,
                                                     const int* __restrict__ conn,
                                                     const int* __restrict__ mem,
                                                     int* __restrict__ out) {
    const int sx = probe_stride(x);
    const int sc = probe_stride(conn);
    const int sm = probe_stride(mem);
    const int n  = blockIdx.x * 256 + threadIdx.x;   // lane = n -> coalesced store
    const int b  = blockIdx.y;
    const int* cp = conn + (size_t)n * NB * sc;
    const int* xr = x + (size_t)b * Tdim * sx;
    uint32_t addr = 0;
#pragma unroll
    for (int j = 0; j < 16; ++j)
        addr = (addr << 1) | (uint32_t)(xr[(size_t)cp[j * sc] * sx] & 1);
    const uint32_t wi = addr / 31u;
    const uint32_t sh = (addr - wi * 31u) * 2u;
    const uint64_t wd = (uint32_t)mem[((size_t)n * WPN + wi) * sm];
    out[(size_t)b * Ndim + n] = (int)((wd >> sh) & 3u);
}

// ---------------------------------------------------------------------------
extern "C" void kernel_launch(void* const* d_in, const int* in_sizes, int n_in,
                              void* d_out, int out_size, void* d_ws, size_t ws_size,
                              hipStream_t stream) {
    const int* x    = (const int*)d_in[0];       // (B, T) 0/1
    const int* conn = (const int*)d_in[1];       // (N, 16) indices < T
    const int* mem  = (const int*)d_in[2];       // (N, WPN), values < 2^31
    int*       out  = (int*)d_out;               // (B, N), read back as np.int32
    uint32_t*  xT   = (uint32_t*)d_ws;           // (B/32, T) bit-planes, 512 KB

    const size_t need = (size_t)(Bdim / 32) * Tdim * sizeof(uint32_t);
    if (ws_size >= need) {
        dim3 g1(Tdim / 256, Bdim / 32);          // 16 x 32 = 512 blocks
        pack_kernel<<<g1, 256, 0, stream>>>(x, xT);
        dim3 g2(Ndim / 16, Bdim / 512);          // 256 x 2 = 512 blocks
        row_kernel<<<g2, 1024, 0, stream>>>(xT, conn, mem, out);
    } else {
        dim3 g3(Ndim / 256, Bdim);               // 16 x 1024 blocks
        direct_kernel<<<g3, 256, 0, stream>>>(x, conn, mem, out);
    }
}